// Round 6
// baseline (173.579 us; speedup 1.0000x reference)
//
#include <hip/hip_runtime.h>

// AFM layer, MI355X gfx950.
// out[b] = sum_p attn_p * s_p,  s_p = sum_d x[i,d]x[j,d]p[d]
// R7 (62.8us): 2 waves/batch, VALU 56%, MFMA 18%, occ 37%, VGPR 64.
// R8/R9 FAILED (237us): cross-iteration ping-pong via lambdas w/ reference
// outs -> C-frags to scratch (WRITE 221MB). No carried frag state.
// R10 FAILED (79us): sp as 2nd MFMA chain -> body tail grew; sp fdot2 trees
// were FREE in the MFMA shadow. Don't add MFMAs.
// R11 FAILED (87us): 4 waves/batch. Occupancy does NOT follow residency
// arithmetic (stuck ~33-38%); halving bodies/wave doubled per-CU setup.
// R12 WIN (57.0us): 1 wave = 1 batch, 0 barriers, setup amortized over 25
// bodies. VALU 53%, MFMA 18.5%, occ 33%, VGPR 64, no spill.
// Model: issue-work-bound at ~53% util; remaining loss = per-body EXPOSED
// serial latency (4-deep MFMA chain + post-C logit tail) at ~3 waves/SIMD.
// R13 (this round): cut exposed chain depth, same issue work, no carried
// state, no extra MFMAs:
//   1. MFMA chain split 2+2 (Ca: kt0,1; Cb: kt2,3), merged C=Ca+Cb. Both
//      chains init from b1h=0.5*b1 (no zero-frag needed; Ca+Cb restores b1).
//   2. xip = xi*p folded once/wave: sp trees = fdot2(xj, xip) depend only on
//      the ds_read -> issue during pk_mul/MFMA lead-in. Reg-neutral (pp->xip).
//   3. Per-body sp shfl DELETED (25x) -> accumulate per-lane half-sums,
//      single shfl_xor(32) on accWS at the end.
//   4. Logit fdot2 as 4 chains of 2 (was 2 chains of 4): shorter post-C tail.
// LDS: R2's padded stride-76 rows, b64 accesses — MEASURED 0 bank conflicts.
// Pair coverage per batch (25 bodies, 780/800 slots):
//   t=1..15 : 32-rotation (nl,(nl+t)&31) all-valid (prod symmetric);
//   t=16    : half-rotation, nl<16;  t=17..24: uniform rows 32..39;
//   cleanup : 8-triangle of fields 32..39 (28 pairs, closed-form unrank).
// __launch_bounds__(256,4): VGPR cap 128 (R3's (256,8) -> spill).

typedef _Float16 f16;
typedef f16 f16x2 __attribute__((ext_vector_type(2)));
typedef f16 f16x4 __attribute__((ext_vector_type(4)));
typedef f16 f16x8 __attribute__((ext_vector_type(8)));
typedef float fx16 __attribute__((ext_vector_type(16)));

#define NF 40
#define NB 8192
#define STR 76   // f16 elements per LDS row (152 B) — conflict-free (R2)

union V8 { f16x8 v8; f16x4 v4[2]; f16x2 v2[4]; };

__global__ __launch_bounds__(256, 4) void afm_kernel(
    const float* __restrict__ x,   // [8192,40,64]
    const float* __restrict__ W1,  // [64,32]
    const float* __restrict__ b1,  // [32]
    const float* __restrict__ w2,  // [32]
    const float* __restrict__ p,   // [64]
    float* __restrict__ out)       // [8192]
{
    __shared__ f16 xh[4][NF * STR];     // 4 batches x 40 x 76 f16 = 24,320 B

    const int tid  = threadIdx.x;
    const int wid  = tid >> 6;          // wave -> private batch
    const int lane = tid & 63;
    const int b    = blockIdx.x * 4 + wid;

    f16* Xs = &xh[wid][0];

    // ---- per-wave staging: this wave's batch only (2560 floats) ----
    // 320 granules of 8 f16 = 5 x 64 lanes exact; zero barriers in kernel.
    const float4* xb = (const float4*)(x + (size_t)b * (NF * 64));
#pragma unroll
    for (int t = 0; t < 5; ++t) {
        int g = t * 64 + lane;                 // granule 0..319 (8 f16 each)
        float4 v0 = xb[g * 2];
        float4 v1 = xb[g * 2 + 1];
        f16x4 lo = { (f16)v0.x, (f16)v0.y, (f16)v0.z, (f16)v0.w };
        f16x4 hi = { (f16)v1.x, (f16)v1.y, (f16)v1.z, (f16)v1.w };
        int row = g >> 3, gg = g & 7;
        f16* dst = Xs + row * STR + gg * 8;
        *(f16x4*)dst = lo;                     // 8B-aligned b64 writes
        *(f16x4*)(dst + 4) = hi;
    }

    const int nl = lane & 31;   // MFMA column / field index base
    const int hh = lane >> 5;   // wave half -> k sub-block + a-row group
    const int h8 = hh * 8;

    // ---- A-frags: W1^T, A[m=a][k=h8+j], d = kt*16 + h8 + j ----
    f16x8 w1f[4];
#pragma unroll
    for (int kt = 0; kt < 4; ++kt)
#pragma unroll
        for (int j = 0; j < 8; ++j)
            w1f[kt][j] = (f16)W1[(kt * 16 + h8 + j) * 32 + nl];

    // ---- b1/2 as SHARED C-init of both 2-deep chains (Ca+Cb restores b1);
    //      w2*log2e packed f16 (exp2 direct) ----
    fx16 b1h;
    f16x2 w2h[8];
#pragma unroll
    for (int r = 0; r < 16; ++r) {
        int a = (r & 3) + 8 * (r >> 2) + 4 * hh;
        b1h[r] = 0.5f * b1[a];
    }
#pragma unroll
    for (int m = 0; m < 8; ++m) {
        int r = 2 * m;
        int a = (r & 3) + 8 * (r >> 2) + 4 * hh;
        f16x2 t2 = { (f16)(w2[a] * 1.44269504f), (f16)(w2[a + 1] * 1.44269504f) };
        w2h[m] = t2;
    }

    // ---- xi frags for row nl; xip = xi*p in fdot2-pair order ----
    f16x4 xif[8];
    {
        const f16* src = Xs + nl * STR + h8;
#pragma unroll
        for (int kt = 0; kt < 4; ++kt) {
            xif[2 * kt]     = *(const f16x4*)(src + kt * 16);
            xif[2 * kt + 1] = *(const f16x4*)(src + kt * 16 + 4);
        }
    }
    f16x2 xip[16];
#pragma unroll
    for (int kt = 0; kt < 4; ++kt) {
        V8 u; u.v4[0] = xif[2 * kt]; u.v4[1] = xif[2 * kt + 1];
#pragma unroll
        for (int m = 0; m < 4; ++m) {
            f16x2 pe = { (f16)p[kt * 16 + h8 + 2 * m], (f16)p[kt * 16 + h8 + 2 * m + 1] };
            xip[kt * 4 + m] = u.v2[m] * pe;
        }
    }

    float accW = 0.f, accWS = 0.f;   // accWS holds k-HALF sums (combined once at end)

    auto body = [&](const f16x4* xi, const f16x2* xp, int jrow, bool valid) {
        const f16* base = Xs + jrow * STR + h8;
        float s[4];
        fx16 Ca, Cb;
#pragma unroll
        for (int kt = 0; kt < 4; ++kt) {
            V8 xj;
            xj.v4[0] = *(const f16x4*)(base + kt * 16);       // ds_read_b64
            xj.v4[1] = *(const f16x4*)(base + kt * 16 + 4);
            // sp partial off the ds_read directly (xip = xi*p) — no pk_mul dep
            float sk = 0.f;
#pragma unroll
            for (int m = 0; m < 4; ++m)
                sk = __builtin_amdgcn_fdot2(xj.v2[m], xp[kt * 4 + m], sk, false);
            s[kt] = sk;                                        // static idx (unrolled)
            V8 pr;
            pr.v4[0] = xi[2 * kt] * xj.v4[0];                  // v_pk_mul_f16
            pr.v4[1] = xi[2 * kt + 1] * xj.v4[1];
            // two 2-deep MFMA chains, both init b1h; pr dies at its MFMA
            if (kt == 0)      Ca = __builtin_amdgcn_mfma_f32_32x32x16_f16(w1f[0], pr.v8, b1h, 0, 0, 0);
            else if (kt == 1) Ca = __builtin_amdgcn_mfma_f32_32x32x16_f16(w1f[1], pr.v8, Ca,  0, 0, 0);
            else if (kt == 2) Cb = __builtin_amdgcn_mfma_f32_32x32x16_f16(w1f[2], pr.v8, b1h, 0, 0, 0);
            else              Cb = __builtin_amdgcn_mfma_f32_32x32x16_f16(w1f[3], pr.v8, Cb,  0, 0, 0);
        }
        float sp = (s[0] + s[1]) + (s[2] + s[3]);              // k-half sum
        fx16 Cs = Ca + Cb;                                     // v_pk_add_f32 x8
        // logit partial: relu(h).(w2*log2e), 4 fdot2 chains of depth 2
        const f16x2 z2 = { (f16)0.f, (f16)0.f };
        float la[4] = { 0.f, 0.f, 0.f, 0.f };
#pragma unroll
        for (int m = 0; m < 8; ++m) {
            f16x2 hm = __builtin_bit_cast(f16x2,
                __builtin_amdgcn_cvt_pkrtz(Cs[2 * m], Cs[2 * m + 1]));
            hm = __builtin_elementwise_max(hm, z2);            // v_pk_max_f16
            la[m & 3] = __builtin_amdgcn_fdot2(hm, w2h[m], la[m & 3], false);
        }
        float l = (la[0] + la[1]) + (la[2] + la[3]);
        l += __shfl_xor(l, 32);     // combine a-halves (needed for w)
        float w = __builtin_amdgcn_exp2f(l);   // max-free softmax (|l| small)
        if (!valid) w = 0.f;
        accW += w;
        accWS = fmaf(w, sp, accWS);            // half-sum accumulate
    };

    // all 24 rotation/uniform bodies + cleanup: this wave's batch, private
    for (int t = 1; t <= 24; ++t) {
        int jrow = (t <= 16) ? ((nl + t) & 31) : (t + 15);
        bool valid = (t != 16) || (nl < 16);
        body(xif, xip, jrow, valid);
    }
    {   // cleanup: 28 pairs among fields 32..39 (lanes nl<28)
        int q = nl < 28 ? nl : 27;
        float disc = 225.0f - 8.0f * (float)q;
        int ii = (int)((15.0f - sqrtf(disc)) * 0.5f);
        if (ii * (15 - ii) / 2 > q) --ii;                 // sqrt 1-ulp fixups
        if ((ii + 1) * (14 - ii) / 2 <= q) ++ii;
        int jj = q - ii * (15 - ii) / 2 + ii + 1;
        int iC = 32 + ii, jC = 32 + jj;                   // pair (iC,jC), iC<jC
        f16x4 xi2[8];
        const f16* src = Xs + iC * STR + h8;
#pragma unroll
        for (int kt = 0; kt < 4; ++kt) {
            xi2[2 * kt]     = *(const f16x4*)(src + kt * 16);
            xi2[2 * kt + 1] = *(const f16x4*)(src + kt * 16 + 4);
        }
        f16x2 xip2[16];
#pragma unroll
        for (int kt = 0; kt < 4; ++kt) {
            V8 u; u.v4[0] = xi2[2 * kt]; u.v4[1] = xi2[2 * kt + 1];
#pragma unroll
            for (int m = 0; m < 4; ++m) {
                f16x2 pe = { (f16)p[kt * 16 + h8 + 2 * m], (f16)p[kt * 16 + h8 + 2 * m + 1] };
                xip2[kt * 4 + m] = u.v2[m] * pe;
            }
        }
        body(xi2, xip2, jC, nl < 28);
    }

    // combine k-halves ONCE (was per-body), then 32-column butterfly
    accWS += __shfl_xor(accWS, 32);
#pragma unroll
    for (int m = 16; m >= 1; m >>= 1) {
        accW  += __shfl_xor(accW, m);
        accWS += __shfl_xor(accWS, m);
    }
    if (lane == 0) out[b] = accWS / accW;
}

extern "C" void kernel_launch(void* const* d_in, const int* in_sizes, int n_in,
                              void* d_out, int out_size, void* d_ws, size_t ws_size,
                              hipStream_t stream) {
    const float* x  = (const float*)d_in[0];
    const float* W1 = (const float*)d_in[1];
    const float* b1 = (const float*)d_in[2];
    const float* w2 = (const float*)d_in[3];
    const float* p  = (const float*)d_in[4];
    float* out = (float*)d_out;
    dim3 grid(NB / 4), block(256);
    hipLaunchKernelGGL(afm_kernel, grid, block, 0, stream, x, W1, b1, w2, p, out);
}

// Round 7
// 152.564 us; speedup vs baseline: 1.1377x; 1.1377x over previous
//
#include <hip/hip_runtime.h>

// AFM layer, MI355X gfx950.
// out[b] = sum_p attn_p * s_p,  s_p = sum_d x[i,d]x[j,d]p[d]
// R7 (62.8us): 2 waves/batch. R8/R9 FAILED (237us): lambda ref-outs -> spill.
// R10 FAILED (79us): sp as 2nd MFMA chain (body tail grew; sp-dots were free).
// R11 FAILED (87us): 4 waves/batch (occupancy won't move; setup doubled).
// R12 WIN (57.0us): 1 wave = 1 batch, 0 barriers, setup amortized over 25
// bodies. VALU 53%, MFMA 18.5%, occ 33%, VGPR 64, WRITE 64KB (no spill).
// R13 FAILED (83us): bundled 4 changes; the 2+2 MFMA chain split kept Ca+Cb
// BOTH live (+16 VGPR peak over R12) -> partial spill (WRITE 64KB->21.8MB).
// Lesson: peak-pressure budget fits ONE live fx16 C-chain; never two.
// R14 (this round): R12 single-4-deep-chain structure + R13's register-
// neutral items only:
//   2. xip = xi*p folded once/wave (replaces pp, same 16 regs): sp fdot2
//      trees consume the ds_read xj directly -> issue in the pk_mul/MFMA
//      lead-in instead of after prod.
//   3. Per-body sp shfl DELETED (25x cross-lane + waitcnt on the accWS
//      path) -> per-lane k-half sums, ONE shfl_xor(32) at the end.
//   4. Logit fdot2 as 4 chains of depth 2 (was 2x4): shorter post-C tail.
// A/B vs R13: if WRITE is still ~20MB the spill was item 2's cleanup path
// (xi2+xip2 co-live), not the chain split -> drop item 2 next.
// LDS: R2's padded stride-76 rows, b64 accesses — MEASURED 0 bank conflicts.
// Pair coverage per batch (25 bodies, 780/800 slots):
//   t=1..15 : 32-rotation (nl,(nl+t)&31) all-valid (prod symmetric);
//   t=16    : half-rotation, nl<16;  t=17..24: uniform rows 32..39;
//   cleanup : 8-triangle of fields 32..39 (28 pairs, closed-form unrank).
// __launch_bounds__(256,4): VGPR cap 128 (R3's (256,8) -> spill).

typedef _Float16 f16;
typedef f16 f16x2 __attribute__((ext_vector_type(2)));
typedef f16 f16x4 __attribute__((ext_vector_type(4)));
typedef f16 f16x8 __attribute__((ext_vector_type(8)));
typedef float fx16 __attribute__((ext_vector_type(16)));

#define NF 40
#define NB 8192
#define STR 76   // f16 elements per LDS row (152 B) — conflict-free (R2)

union V8 { f16x8 v8; f16x4 v4[2]; f16x2 v2[4]; };

__global__ __launch_bounds__(256, 4) void afm_kernel(
    const float* __restrict__ x,   // [8192,40,64]
    const float* __restrict__ W1,  // [64,32]
    const float* __restrict__ b1,  // [32]
    const float* __restrict__ w2,  // [32]
    const float* __restrict__ p,   // [64]
    float* __restrict__ out)       // [8192]
{
    __shared__ f16 xh[4][NF * STR];     // 4 batches x 40 x 76 f16 = 24,320 B

    const int tid  = threadIdx.x;
    const int wid  = tid >> 6;          // wave -> private batch
    const int lane = tid & 63;
    const int b    = blockIdx.x * 4 + wid;

    f16* Xs = &xh[wid][0];

    // ---- per-wave staging: this wave's batch only (2560 floats) ----
    // 320 granules of 8 f16 = 5 x 64 lanes exact; zero barriers in kernel.
    const float4* xb = (const float4*)(x + (size_t)b * (NF * 64));
#pragma unroll
    for (int t = 0; t < 5; ++t) {
        int g = t * 64 + lane;                 // granule 0..319 (8 f16 each)
        float4 v0 = xb[g * 2];
        float4 v1 = xb[g * 2 + 1];
        f16x4 lo = { (f16)v0.x, (f16)v0.y, (f16)v0.z, (f16)v0.w };
        f16x4 hi = { (f16)v1.x, (f16)v1.y, (f16)v1.z, (f16)v1.w };
        int row = g >> 3, gg = g & 7;
        f16* dst = Xs + row * STR + gg * 8;
        *(f16x4*)dst = lo;                     // 8B-aligned b64 writes
        *(f16x4*)(dst + 4) = hi;
    }

    const int nl = lane & 31;   // MFMA column / field index base
    const int hh = lane >> 5;   // wave half -> k sub-block + a-row group
    const int h8 = hh * 8;

    // ---- A-frags: W1^T, A[m=a][k=h8+j], d = kt*16 + h8 + j ----
    f16x8 w1f[4];
#pragma unroll
    for (int kt = 0; kt < 4; ++kt)
#pragma unroll
        for (int j = 0; j < 8; ++j)
            w1f[kt][j] = (f16)W1[(kt * 16 + h8 + j) * 32 + nl];

    // ---- b1 as persistent C-frag; w2*log2e packed f16 (exp2 direct) ----
    fx16 b1C;
    f16x2 w2h[8];
#pragma unroll
    for (int r = 0; r < 16; ++r) {
        int a = (r & 3) + 8 * (r >> 2) + 4 * hh;
        b1C[r] = b1[a];
    }
#pragma unroll
    for (int m = 0; m < 8; ++m) {
        int r = 2 * m;
        int a = (r & 3) + 8 * (r >> 2) + 4 * hh;
        f16x2 t2 = { (f16)(w2[a] * 1.44269504f), (f16)(w2[a + 1] * 1.44269504f) };
        w2h[m] = t2;
    }

    // ---- xi frags for row nl; xip = xi*p in fdot2-pair order ----
    f16x4 xif[8];
    {
        const f16* src = Xs + nl * STR + h8;
#pragma unroll
        for (int kt = 0; kt < 4; ++kt) {
            xif[2 * kt]     = *(const f16x4*)(src + kt * 16);
            xif[2 * kt + 1] = *(const f16x4*)(src + kt * 16 + 4);
        }
    }
    f16x2 xip[16];
#pragma unroll
    for (int kt = 0; kt < 4; ++kt) {
        V8 u; u.v4[0] = xif[2 * kt]; u.v4[1] = xif[2 * kt + 1];
#pragma unroll
        for (int m = 0; m < 4; ++m) {
            f16x2 pe = { (f16)p[kt * 16 + h8 + 2 * m], (f16)p[kt * 16 + h8 + 2 * m + 1] };
            xip[kt * 4 + m] = u.v2[m] * pe;
        }
    }

    float accW = 0.f, accWS = 0.f;   // accWS = k-HALF sums (combined at end)

    auto body = [&](const f16x4* xi, const f16x2* xp, int jrow, bool valid) {
        const f16* base = Xs + jrow * STR + h8;
        V8 pr[4];
        float s0 = 0.f, s1 = 0.f, s2 = 0.f, s3 = 0.f;
#pragma unroll
        for (int kt = 0; kt < 4; ++kt) {
            V8 xj;
            xj.v4[0] = *(const f16x4*)(base + kt * 16);       // ds_read_b64
            xj.v4[1] = *(const f16x4*)(base + kt * 16 + 4);
            // sp partials straight off the ds_read (xip = xi*p): 4 parallel
            // trees by kt, independent of the pk_mul/MFMA stream
            float* sk = (kt == 0) ? &s0 : (kt == 1) ? &s1 : (kt == 2) ? &s2 : &s3;
#pragma unroll
            for (int m = 0; m < 4; ++m)
                *sk = __builtin_amdgcn_fdot2(xj.v2[m], xp[kt * 4 + m], *sk, false);
            pr[kt].v4[0] = xi[2 * kt] * xj.v4[0];              // v_pk_mul_f16
            pr[kt].v4[1] = xi[2 * kt + 1] * xj.v4[1];
        }
        // h = W1^T prod + b1 : single 4-deep chain from persistent b1 frag
        // (ONE live fx16 — the R13 2-chain split spilled)
        fx16 C = __builtin_amdgcn_mfma_f32_32x32x16_f16(w1f[0], pr[0].v8, b1C, 0, 0, 0);
        C = __builtin_amdgcn_mfma_f32_32x32x16_f16(w1f[1], pr[1].v8, C, 0, 0, 0);
        C = __builtin_amdgcn_mfma_f32_32x32x16_f16(w1f[2], pr[2].v8, C, 0, 0, 0);
        C = __builtin_amdgcn_mfma_f32_32x32x16_f16(w1f[3], pr[3].v8, C, 0, 0, 0);
        float sp = (s0 + s1) + (s2 + s3);                      // k-half sum
        // logit partial: relu(h).(w2*log2e), 4 fdot2 chains of depth 2
        const f16x2 z2 = { (f16)0.f, (f16)0.f };
        float la[4] = { 0.f, 0.f, 0.f, 0.f };
#pragma unroll
        for (int m = 0; m < 8; ++m) {
            f16x2 hm = __builtin_bit_cast(f16x2,
                __builtin_amdgcn_cvt_pkrtz(C[2 * m], C[2 * m + 1]));
            hm = __builtin_elementwise_max(hm, z2);            // v_pk_max_f16
            la[m & 3] = __builtin_amdgcn_fdot2(hm, w2h[m], la[m & 3], false);
        }
        float l = (la[0] + la[1]) + (la[2] + la[3]);
        l += __shfl_xor(l, 32);     // combine a-halves (needed for w)
        float w = __builtin_amdgcn_exp2f(l);   // max-free softmax (|l| small)
        if (!valid) w = 0.f;
        accW += w;
        accWS = fmaf(w, sp, accWS);            // half-sum accumulate (no shfl)
    };

    // all 24 rotation/uniform bodies + cleanup: this wave's batch, private
    for (int t = 1; t <= 24; ++t) {
        int jrow = (t <= 16) ? ((nl + t) & 31) : (t + 15);
        bool valid = (t != 16) || (nl < 16);
        body(xif, xip, jrow, valid);
    }
    {   // cleanup: 28 pairs among fields 32..39 (lanes nl<28)
        int q = nl < 28 ? nl : 27;
        float disc = 225.0f - 8.0f * (float)q;
        int ii = (int)((15.0f - sqrtf(disc)) * 0.5f);
        if (ii * (15 - ii) / 2 > q) --ii;                 // sqrt 1-ulp fixups
        if ((ii + 1) * (14 - ii) / 2 <= q) ++ii;
        int jj = q - ii * (15 - ii) / 2 + ii + 1;
        int iC = 32 + ii, jC = 32 + jj;                   // pair (iC,jC), iC<jC
        f16x4 xi2[8];
        const f16* src = Xs + iC * STR + h8;
#pragma unroll
        for (int kt = 0; kt < 4; ++kt) {
            xi2[2 * kt]     = *(const f16x4*)(src + kt * 16);
            xi2[2 * kt + 1] = *(const f16x4*)(src + kt * 16 + 4);
        }
        f16x2 xip2[16];
#pragma unroll
        for (int kt = 0; kt < 4; ++kt) {
            V8 u; u.v4[0] = xi2[2 * kt]; u.v4[1] = xi2[2 * kt + 1];
#pragma unroll
            for (int m = 0; m < 4; ++m) {
                f16x2 pe = { (f16)p[kt * 16 + h8 + 2 * m], (f16)p[kt * 16 + h8 + 2 * m + 1] };
                xip2[kt * 4 + m] = u.v2[m] * pe;
            }
        }
        body(xi2, xip2, jC, nl < 28);
    }

    // combine k-halves ONCE (was per-body), then 32-column butterfly
    accWS += __shfl_xor(accWS, 32);
#pragma unroll
    for (int m = 16; m >= 1; m >>= 1) {
        accW  += __shfl_xor(accW, m);
        accWS += __shfl_xor(accWS, m);
    }
    if (lane == 0) out[b] = accWS / accW;
}

extern "C" void kernel_launch(void* const* d_in, const int* in_sizes, int n_in,
                              void* d_out, int out_size, void* d_ws, size_t ws_size,
                              hipStream_t stream) {
    const float* x  = (const float*)d_in[0];
    const float* W1 = (const float*)d_in[1];
    const float* b1 = (const float*)d_in[2];
    const float* w2 = (const float*)d_in[3];
    const float* p  = (const float*)d_in[4];
    float* out = (float*)d_out;
    dim3 grid(NB / 4), block(256);
    hipLaunchKernelGGL(afm_kernel, grid, block, 0, stream, x, W1, b1, w2, p, out);
}

// Round 8
// 151.585 us; speedup vs baseline: 1.1451x; 1.0065x over previous
//
#include <hip/hip_runtime.h>

// AFM layer, MI355X gfx950.
// out[b] = sum_p attn_p * s_p,  s_p = sum_d x[i,d]x[j,d]p[d]
// R7 (62.8us): 2 waves/batch. R8/R9 FAILED (237us): lambda ref-outs -> spill.
// R10 FAILED (79us): sp as 2nd MFMA chain (body tail grew; sp-dots were free).
// R11 FAILED (87us): 4 waves/batch (occupancy won't move; setup doubled).
// R12 WIN (57.0us): 1 wave = 1 batch, 0 barriers, setup amortized over 25
// bodies. VALU 53%, MFMA 18.5%, occ 33%, VGPR 64, WRITE 64KB (no spill).
// R13 FAILED (83us): 2+2 MFMA chain split -> Ca+Cb both live (+16 VGPR peak)
// -> partial spill (WRITE 21.8MB). Peak budget fits ONE live fx16 chain.
// R14 FAILED (65.2us): no spill, but xip reordering put the 16 sp-fdot2s
// BETWEEN ds_read and pk_mul, delaying MFMA-chain issue every body. Lesson
// (mirror of R10): sp-dots must sit AFTER the MFMA issues, in its shadow.
// R15 (this round): exact R12 body schedule + two register-neutral tail cuts:
//   a. per-body l-combine via v_permlane32_swap_b32 (VALU ~6cyc) instead of
//      __shfl_xor's ds_bpermute (~30+cyc lgkm wait) — the l-shfl is on the
//      terminal dependency (C->logit->combine->exp2->acc) 25x per wave.
//   b. per-body sp shfl DELETED: accWS accumulates k-half sums; single
//      shfl_xor(accWS,32) at the end. Removes 25 LDS-pipe ops, no chain grows.
// LDS: R2's padded stride-76 rows, b64 accesses — MEASURED 0 bank conflicts.
// Pair coverage per batch (25 bodies, 780/800 slots):
//   t=1..15 : 32-rotation (nl,(nl+t)&31) all-valid (prod symmetric);
//   t=16    : half-rotation, nl<16;  t=17..24: uniform rows 32..39;
//   cleanup : 8-triangle of fields 32..39 (28 pairs, closed-form unrank).
// __launch_bounds__(256,4): VGPR cap 128 (R3's (256,8) -> spill).

typedef _Float16 f16;
typedef f16 f16x2 __attribute__((ext_vector_type(2)));
typedef f16 f16x4 __attribute__((ext_vector_type(4)));
typedef f16 f16x8 __attribute__((ext_vector_type(8)));
typedef float fx16 __attribute__((ext_vector_type(16)));

#define NF 40
#define NB 8192
#define STR 76   // f16 elements per LDS row (152 B) — conflict-free (R2)

union V8 { f16x8 v8; f16x4 v4[2]; f16x2 v2[4]; };

__global__ __launch_bounds__(256, 4) void afm_kernel(
    const float* __restrict__ x,   // [8192,40,64]
    const float* __restrict__ W1,  // [64,32]
    const float* __restrict__ b1,  // [32]
    const float* __restrict__ w2,  // [32]
    const float* __restrict__ p,   // [64]
    float* __restrict__ out)       // [8192]
{
    __shared__ f16 xh[4][NF * STR];     // 4 batches x 40 x 76 f16 = 24,320 B

    const int tid  = threadIdx.x;
    const int wid  = tid >> 6;          // wave -> private batch
    const int lane = tid & 63;
    const int b    = blockIdx.x * 4 + wid;

    f16* Xs = &xh[wid][0];

    // ---- per-wave staging: this wave's batch only (2560 floats) ----
    // 320 granules of 8 f16 = 5 x 64 lanes exact; zero barriers in kernel.
    const float4* xb = (const float4*)(x + (size_t)b * (NF * 64));
#pragma unroll
    for (int t = 0; t < 5; ++t) {
        int g = t * 64 + lane;                 // granule 0..319 (8 f16 each)
        float4 v0 = xb[g * 2];
        float4 v1 = xb[g * 2 + 1];
        f16x4 lo = { (f16)v0.x, (f16)v0.y, (f16)v0.z, (f16)v0.w };
        f16x4 hi = { (f16)v1.x, (f16)v1.y, (f16)v1.z, (f16)v1.w };
        int row = g >> 3, gg = g & 7;
        f16* dst = Xs + row * STR + gg * 8;
        *(f16x4*)dst = lo;                     // 8B-aligned b64 writes
        *(f16x4*)(dst + 4) = hi;
    }

    const int nl = lane & 31;   // MFMA column / field index base
    const int hh = lane >> 5;   // wave half -> k sub-block + a-row group
    const int h8 = hh * 8;

    // ---- A-frags: W1^T, A[m=a][k=h8+j], d = kt*16 + h8 + j ----
    f16x8 w1f[4];
#pragma unroll
    for (int kt = 0; kt < 4; ++kt)
#pragma unroll
        for (int j = 0; j < 8; ++j)
            w1f[kt][j] = (f16)W1[(kt * 16 + h8 + j) * 32 + nl];

    // ---- p packed to match prod-frag element order (for fdot2) ----
    f16x2 pp[16];
#pragma unroll
    for (int kt = 0; kt < 4; ++kt)
#pragma unroll
        for (int m = 0; m < 4; ++m) {
            f16x2 t2 = { (f16)p[kt * 16 + h8 + 2 * m], (f16)p[kt * 16 + h8 + 2 * m + 1] };
            pp[kt * 4 + m] = t2;
        }

    // ---- b1 as persistent C-frag; w2*log2e packed f16 (exp2 direct) ----
    fx16 b1C;
    f16x2 w2h[8];
#pragma unroll
    for (int r = 0; r < 16; ++r) {
        int a = (r & 3) + 8 * (r >> 2) + 4 * hh;
        b1C[r] = b1[a];
    }
#pragma unroll
    for (int m = 0; m < 8; ++m) {
        int r = 2 * m;
        int a = (r & 3) + 8 * (r >> 2) + 4 * hh;
        f16x2 t2 = { (f16)(w2[a] * 1.44269504f), (f16)(w2[a + 1] * 1.44269504f) };
        w2h[m] = t2;
    }

    // ---- xi frags for row nl ----
    f16x4 xif[8];
    {
        const f16* src = Xs + nl * STR + h8;
#pragma unroll
        for (int kt = 0; kt < 4; ++kt) {
            xif[2 * kt]     = *(const f16x4*)(src + kt * 16);
            xif[2 * kt + 1] = *(const f16x4*)(src + kt * 16 + 4);
        }
    }

    float accW = 0.f, accWS = 0.f;   // accWS = k-HALF sums (combined at end)

    auto body = [&](const f16x4* xi, int jrow, bool valid) {
        const f16* base = Xs + jrow * STR + h8;
        V8 pr[4];
#pragma unroll
        for (int kt = 0; kt < 4; ++kt) {
            f16x4 a0 = *(const f16x4*)(base + kt * 16);       // ds_read_b64
            f16x4 a1 = *(const f16x4*)(base + kt * 16 + 4);
            pr[kt].v4[0] = xi[2 * kt] * a0;                    // v_pk_mul_f16
            pr[kt].v4[1] = xi[2 * kt + 1] * a1;
        }
        // h = W1^T prod + b1 : single 4-deep chain from persistent b1 frag
        fx16 C = __builtin_amdgcn_mfma_f32_32x32x16_f16(w1f[0], pr[0].v8, b1C, 0, 0, 0);
        C = __builtin_amdgcn_mfma_f32_32x32x16_f16(w1f[1], pr[1].v8, C, 0, 0, 0);
        C = __builtin_amdgcn_mfma_f32_32x32x16_f16(w1f[2], pr[2].v8, C, 0, 0, 0);
        C = __builtin_amdgcn_mfma_f32_32x32x16_f16(w1f[3], pr[3].v8, C, 0, 0, 0);
        // s_p partial: 4 parallel fdot2 trees — free inside the MFMA shadow
        // (R14 lesson: these must come AFTER the MFMA issues, not before)
        float s0 = 0.f, s1 = 0.f, s2 = 0.f, s3 = 0.f;
#pragma unroll
        for (int m = 0; m < 4; ++m) {
            s0 = __builtin_amdgcn_fdot2(pr[0].v2[m], pp[m],      s0, false);
            s1 = __builtin_amdgcn_fdot2(pr[1].v2[m], pp[4 + m],  s1, false);
            s2 = __builtin_amdgcn_fdot2(pr[2].v2[m], pp[8 + m],  s2, false);
            s3 = __builtin_amdgcn_fdot2(pr[3].v2[m], pp[12 + m], s3, false);
        }
        float sp = (s0 + s1) + (s2 + s3);                      // k-half sum
        // logit partial: relu(h).(w2*log2e) in packed f16, 2 parallel trees
        const f16x2 z2 = { (f16)0.f, (f16)0.f };
        float l0 = 0.f, l1 = 0.f;
#pragma unroll
        for (int m = 0; m < 8; ++m) {
            f16x2 hm = __builtin_bit_cast(f16x2,
                __builtin_amdgcn_cvt_pkrtz(C[2 * m], C[2 * m + 1]));
            hm = __builtin_elementwise_max(hm, z2);            // v_pk_max_f16
            if (m & 1) l1 = __builtin_amdgcn_fdot2(hm, w2h[m], l1, false);
            else       l0 = __builtin_amdgcn_fdot2(hm, w2h[m], l0, false);
        }
        float l = l0 + l1;
        // a-halves combine on the terminal path: v_permlane32_swap_b32
        // (VALU) instead of __shfl_xor's ds_bpermute + lgkm wait.
        // swap semantics: new_a[i>=32]=old_b[i-32]; new_b[i<32]=old_a[i+32]
        // -> partner(l)[i] = (i<32) ? r1[i] : r0[i]
        {
            unsigned lu = __builtin_bit_cast(unsigned, l);
            auto r = __builtin_amdgcn_permlane32_swap(lu, lu, false, false);
            unsigned r0, r1;
            __builtin_memcpy(&r0, &r, 4);                      // new vdst
            __builtin_memcpy(&r1, (const char*)&r + 4, 4);     // new vsrc
            l += __builtin_bit_cast(float, hh ? r0 : r1);
        }
        float w = __builtin_amdgcn_exp2f(l);   // max-free softmax (|l| small)
        if (!valid) w = 0.f;
        accW += w;
        accWS = fmaf(w, sp, accWS);            // k-half accumulate (no shfl)
    };

    // all 24 rotation/uniform bodies + cleanup: this wave's batch, private
    for (int t = 1; t <= 24; ++t) {
        int jrow = (t <= 16) ? ((nl + t) & 31) : (t + 15);
        bool valid = (t != 16) || (nl < 16);
        body(xif, jrow, valid);
    }
    {   // cleanup: 28 pairs among fields 32..39 (lanes nl<28)
        int q = nl < 28 ? nl : 27;
        float disc = 225.0f - 8.0f * (float)q;
        int ii = (int)((15.0f - sqrtf(disc)) * 0.5f);
        if (ii * (15 - ii) / 2 > q) --ii;                 // sqrt 1-ulp fixups
        if ((ii + 1) * (14 - ii) / 2 <= q) ++ii;
        int jj = q - ii * (15 - ii) / 2 + ii + 1;
        int iC = 32 + ii, jC = 32 + jj;                   // pair (iC,jC), iC<jC
        f16x4 xi2[8];
        const f16* src = Xs + iC * STR + h8;
#pragma unroll
        for (int kt = 0; kt < 4; ++kt) {
            xi2[2 * kt]     = *(const f16x4*)(src + kt * 16);
            xi2[2 * kt + 1] = *(const f16x4*)(src + kt * 16 + 4);
        }
        body(xi2, jC, nl < 28);
    }

    // combine k-halves ONCE (was per-body), then 32-column butterfly
    accWS += __shfl_xor(accWS, 32);
#pragma unroll
    for (int m = 16; m >= 1; m >>= 1) {
        accW  += __shfl_xor(accW, m);
        accWS += __shfl_xor(accWS, m);
    }
    if (lane == 0) out[b] = accWS / accW;
}

extern "C" void kernel_launch(void* const* d_in, const int* in_sizes, int n_in,
                              void* d_out, int out_size, void* d_ws, size_t ws_size,
                              hipStream_t stream) {
    const float* x  = (const float*)d_in[0];
    const float* W1 = (const float*)d_in[1];
    const float* b1 = (const float*)d_in[2];
    const float* w2 = (const float*)d_in[3];
    const float* p  = (const float*)d_in[4];
    float* out = (float*)d_out;
    dim3 grid(NB / 4), block(256);
    hipLaunchKernelGGL(afm_kernel, grid, block, 0, stream, x, W1, b1, w2, p, out);
}

// Round 9
// 151.267 us; speedup vs baseline: 1.1475x; 1.0021x over previous
//
#include <hip/hip_runtime.h>

// AFM layer, MI355X gfx950.
// out[b] = sum_p attn_p * s_p,  s_p = sum_d x[i,d]x[j,d]p[d]
// R7 (62.8us): 2 waves/batch. R8/R9 FAILED (237us): lambda ref-outs -> spill.
// R10 FAILED (79us): sp as 2nd MFMA chain (body tail grew; sp-dots were free).
// R11 FAILED (87us): 4 waves/batch (occupancy won't move; setup doubled).
// R12 WIN (57.0us): 1 wave = 1 batch, 0 barriers, setup amortized over 25
// bodies. VALU 53%, MFMA 18.5%, occ 33%, VGPR 64, WRITE 64KB (no spill).
// R13 FAILED (83us): 2+2 MFMA split -> 2 live fx16 -> partial spill.
// R14 FAILED (65us): xip put sp-dots before MFMA issue -> delayed chain.
// R15 NULL (58.6us): permlane l-combine + sp-shfl deletion -> no gain.
// Model locked by R12/R14/R15: per-wave latency is TLP-covered; the SIMD
// ISSUE PORT is the binding resource (~80%: VALU 54% + ds ~14% + MFMA ~7%
// + trans/SALU). Only instruction-SLOT deletion pays.
// R16 (this round): delete ds_read slots. 8x ds_read_b64 -> 4x ds_read_b128
// per body (+xif 8->4, staging writes 2->1 per granule): ~130 slots/wave.
//   STR 76 -> 88 (176B rows): 16B-aligned for b128; granule-level banks =
//   (3*row + col) mod 8, gcd(3,8)=1 -> 32 rotation rows spread UNIFORMLY
//   over 8 bank-groups = b128's inherent 4-phase floor, no extra conflict
//   (R4's b128 regression used a non-uniform swizzle; gate = conflict ctr).
//   Input f32->f16 stays scalar RNE cvt (cvt_pkrtz is RTZ; absmax has no
//   rounding headroom). l-combine back to plain __shfl_xor (R15's permlane
//   pair-return+select junk cost more than it saved); sp-shfl stays deleted
//   (k-half sums, one end shfl — pure slot deletion, proven in R15).
// LDS: 4 x 40 x 88 f16 = 28,160 B. Zero barriers (per-wave private slices).
// Pair coverage per batch (25 bodies, 780/800 slots):
//   t=1..15 : 32-rotation (nl,(nl+t)&31) all-valid (prod symmetric);
//   t=16    : half-rotation, nl<16;  t=17..24: uniform rows 32..39;
//   cleanup : 8-triangle of fields 32..39 (28 pairs, closed-form unrank).
// __launch_bounds__(256,4): VGPR cap 128 (R3's (256,8) -> spill).

typedef _Float16 f16;
typedef f16 f16x2 __attribute__((ext_vector_type(2)));
typedef f16 f16x4 __attribute__((ext_vector_type(4)));
typedef f16 f16x8 __attribute__((ext_vector_type(8)));
typedef float fx16 __attribute__((ext_vector_type(16)));

#define NF 40
#define NB 8192
#define STR 88   // f16 elements per LDS row (176 B): 16B-aligned b128 rows,
                 // uniform bank-group spread (3r+c mod 8) at granule level

union V8 { f16x8 v8; f16x4 v4[2]; f16x2 v2[4]; };

__global__ __launch_bounds__(256, 4) void afm_kernel(
    const float* __restrict__ x,   // [8192,40,64]
    const float* __restrict__ W1,  // [64,32]
    const float* __restrict__ b1,  // [32]
    const float* __restrict__ w2,  // [32]
    const float* __restrict__ p,   // [64]
    float* __restrict__ out)       // [8192]
{
    __shared__ __align__(16) f16 xh[4][NF * STR];   // 28,160 B

    const int tid  = threadIdx.x;
    const int wid  = tid >> 6;          // wave -> private batch
    const int lane = tid & 63;
    const int b    = blockIdx.x * 4 + wid;

    f16* Xs = &xh[wid][0];

    // ---- per-wave staging: this wave's batch only (2560 floats) ----
    // 320 granules of 8 f16 = 5 x 64 lanes exact; zero barriers in kernel.
    // One ds_write_b128 per granule (dst = row*176 + gg*16, 16B-aligned).
    const float4* xb = (const float4*)(x + (size_t)b * (NF * 64));
#pragma unroll
    for (int t = 0; t < 5; ++t) {
        int g = t * 64 + lane;                 // granule 0..319 (8 f16 each)
        float4 v0 = xb[g * 2];
        float4 v1 = xb[g * 2 + 1];
        V8 w;                                   // scalar RNE converts (x8)
        w.v4[0] = f16x4{ (f16)v0.x, (f16)v0.y, (f16)v0.z, (f16)v0.w };
        w.v4[1] = f16x4{ (f16)v1.x, (f16)v1.y, (f16)v1.z, (f16)v1.w };
        int row = g >> 3, gg = g & 7;
        *(f16x8*)(Xs + row * STR + gg * 8) = w.v8;   // ds_write_b128
    }

    const int nl = lane & 31;   // MFMA column / field index base
    const int hh = lane >> 5;   // wave half -> k sub-block + a-row group
    const int h8 = hh * 8;

    // ---- A-frags: W1^T, A[m=a][k=h8+j], d = kt*16 + h8 + j ----
    f16x8 w1f[4];
#pragma unroll
    for (int kt = 0; kt < 4; ++kt)
#pragma unroll
        for (int j = 0; j < 8; ++j)
            w1f[kt][j] = (f16)W1[(kt * 16 + h8 + j) * 32 + nl];

    // ---- p packed to match prod-frag element order (for fdot2) ----
    f16x2 pp[16];
#pragma unroll
    for (int kt = 0; kt < 4; ++kt)
#pragma unroll
        for (int m = 0; m < 4; ++m) {
            f16x2 t2 = { (f16)p[kt * 16 + h8 + 2 * m], (f16)p[kt * 16 + h8 + 2 * m + 1] };
            pp[kt * 4 + m] = t2;
        }

    // ---- b1 as persistent C-frag; w2*log2e packed f16 (exp2 direct) ----
    fx16 b1C;
    f16x2 w2h[8];
#pragma unroll
    for (int r = 0; r < 16; ++r) {
        int a = (r & 3) + 8 * (r >> 2) + 4 * hh;
        b1C[r] = b1[a];
    }
#pragma unroll
    for (int m = 0; m < 8; ++m) {
        int r = 2 * m;
        int a = (r & 3) + 8 * (r >> 2) + 4 * hh;
        f16x2 t2 = { (f16)(w2[a] * 1.44269504f), (f16)(w2[a + 1] * 1.44269504f) };
        w2h[m] = t2;
    }

    // ---- xi frags for row nl: 4 x ds_read_b128 ----
    f16x8 xif8[4];
    {
        const f16* src = Xs + nl * STR + h8;
#pragma unroll
        for (int kt = 0; kt < 4; ++kt)
            xif8[kt] = *(const f16x8*)(src + kt * 16);
    }

    float accW = 0.f, accWS = 0.f;   // accWS = k-HALF sums (combined at end)

    auto body = [&](const f16x8* xi, int jrow, bool valid) {
        const f16* base = Xs + jrow * STR + h8;
        V8 pr[4];
#pragma unroll
        for (int kt = 0; kt < 4; ++kt) {
            f16x8 xj = *(const f16x8*)(base + kt * 16);        // ds_read_b128
            pr[kt].v8 = xi[kt] * xj;                           // v_pk_mul_f16 x4
        }
        // h = W1^T prod + b1 : single 4-deep chain from persistent b1 frag
        fx16 C = __builtin_amdgcn_mfma_f32_32x32x16_f16(w1f[0], pr[0].v8, b1C, 0, 0, 0);
        C = __builtin_amdgcn_mfma_f32_32x32x16_f16(w1f[1], pr[1].v8, C, 0, 0, 0);
        C = __builtin_amdgcn_mfma_f32_32x32x16_f16(w1f[2], pr[2].v8, C, 0, 0, 0);
        C = __builtin_amdgcn_mfma_f32_32x32x16_f16(w1f[3], pr[3].v8, C, 0, 0, 0);
        // s_p partial: 4 parallel fdot2 trees — in the MFMA shadow
        // (R14 lesson: AFTER the MFMA issues, not before)
        float s0 = 0.f, s1 = 0.f, s2 = 0.f, s3 = 0.f;
#pragma unroll
        for (int m = 0; m < 4; ++m) {
            s0 = __builtin_amdgcn_fdot2(pr[0].v2[m], pp[m],      s0, false);
            s1 = __builtin_amdgcn_fdot2(pr[1].v2[m], pp[4 + m],  s1, false);
            s2 = __builtin_amdgcn_fdot2(pr[2].v2[m], pp[8 + m],  s2, false);
            s3 = __builtin_amdgcn_fdot2(pr[3].v2[m], pp[12 + m], s3, false);
        }
        float sp = (s0 + s1) + (s2 + s3);                      // k-half sum
        // logit partial: relu(h).(w2*log2e) in packed f16, 2 parallel trees
        const f16x2 z2 = { (f16)0.f, (f16)0.f };
        float l0 = 0.f, l1 = 0.f;
#pragma unroll
        for (int m = 0; m < 8; ++m) {
            f16x2 hm = __builtin_bit_cast(f16x2,
                __builtin_amdgcn_cvt_pkrtz(C[2 * m], C[2 * m + 1]));
            hm = __builtin_elementwise_max(hm, z2);            // v_pk_max_f16
            if (m & 1) l1 = __builtin_amdgcn_fdot2(hm, w2h[m], l1, false);
            else       l0 = __builtin_amdgcn_fdot2(hm, w2h[m], l0, false);
        }
        float l = l0 + l1;
        l += __shfl_xor(l, 32);     // combine a-halves (plain shfl — R15's
                                    // permlane pair/select was net negative)
        float w = __builtin_amdgcn_exp2f(l);   // max-free softmax (|l| small)
        if (!valid) w = 0.f;
        accW += w;
        accWS = fmaf(w, sp, accWS);            // k-half accumulate (no shfl)
    };

    // all 24 rotation/uniform bodies + cleanup: this wave's batch, private
    for (int t = 1; t <= 24; ++t) {
        int jrow = (t <= 16) ? ((nl + t) & 31) : (t + 15);
        bool valid = (t != 16) || (nl < 16);
        body(xif8, jrow, valid);
    }
    {   // cleanup: 28 pairs among fields 32..39 (lanes nl<28)
        int q = nl < 28 ? nl : 27;
        float disc = 225.0f - 8.0f * (float)q;
        int ii = (int)((15.0f - sqrtf(disc)) * 0.5f);
        if (ii * (15 - ii) / 2 > q) --ii;                 // sqrt 1-ulp fixups
        if ((ii + 1) * (14 - ii) / 2 <= q) ++ii;
        int jj = q - ii * (15 - ii) / 2 + ii + 1;
        int iC = 32 + ii, jC = 32 + jj;                   // pair (iC,jC), iC<jC
        f16x8 xi2[4];
        const f16* src = Xs + iC * STR + h8;
#pragma unroll
        for (int kt = 0; kt < 4; ++kt)
            xi2[kt] = *(const f16x8*)(src + kt * 16);
        body(xi2, jC, nl < 28);
    }

    // combine k-halves ONCE, then 32-column butterfly
    accWS += __shfl_xor(accWS, 32);
#pragma unroll
    for (int m = 16; m >= 1; m >>= 1) {
        accW  += __shfl_xor(accW, m);
        accWS += __shfl_xor(accWS, m);
    }
    if (lane == 0) out[b] = accWS / accW;
}

extern "C" void kernel_launch(void* const* d_in, const int* in_sizes, int n_in,
                              void* d_out, int out_size, void* d_ws, size_t ws_size,
                              hipStream_t stream) {
    const float* x  = (const float*)d_in[0];
    const float* W1 = (const float*)d_in[1];
    const float* b1 = (const float*)d_in[2];
    const float* w2 = (const float*)d_in[3];
    const float* p  = (const float*)d_in[4];
    float* out = (float*)d_out;
    dim3 grid(NB / 4), block(256);
    hipLaunchKernelGGL(afm_kernel, grid, block, 0, stream, x, W1, b1, w2, p, out);
}